// Round 3
// baseline (113.414 us; speedup 1.0000x reference)
//
#include <hip/hip_runtime.h>
#include <math.h>

// MoELoRA dims (fixed by the problem)
#define NTOK   16384      // B*S
#define DDIM   1024
#define NE     8
#define NF     128        // E*G*R down-proj features (f = e*16 + g*8 + r)
#define FP     144        // GEMM1 N: 128 h + 8 logits + 8 zero  (9 MFMA N-tiles)
#define ODIM   1024
#define NOUT   3072
#define SCALE  2.0f
#define TOKB   32         // tokens per block -> 512 blocks (2 per CU)

typedef __attribute__((ext_vector_type(8))) short bf16x8;
typedef __attribute__((ext_vector_type(4))) float f32x4;

// ws layout (bytes)
#define WS_ABT 0                        // bf16 [144][1024]   = 294912 B
#define WS_BBT 294912                   // bf16 [2][1024][64] = 262144 B

// pack two fp32 -> (bf16(a) | bf16(b)<<16), round-to-nearest-even
__device__ inline unsigned f2bf(float a, float b) {
    union { float f; unsigned u; } ua, ub;
    ua.f = a; ub.f = b;
    unsigned x = ua.u + (0x7fffu + ((ua.u >> 16) & 1));
    unsigned y = ub.u + (0x7fffu + ((ub.u >> 16) & 1));
    return (x >> 16) | (y & 0xffff0000u);
}

// ---------------------------------------------------------------------------
// Prep: Abt[f][d] = bf16(concat(A, W_route, 0))   (A is already f-major)
//       Bbt[g][o][er] = bf16(Bw[e][g][o][r]), er = e*8+r
__global__ __launch_bounds__(256) void k_prep(const float* __restrict__ A,
                                              const float* __restrict__ Wr,
                                              const float* __restrict__ Bw,
                                              unsigned short* __restrict__ Abt,
                                              unsigned short* __restrict__ Bbt) {
    const int b = blockIdx.x, t = threadIdx.x;
    if (b < FP) {
        const int col = t * 4;
        float4 v = {0.f, 0.f, 0.f, 0.f};
        if (b < NF)           v = *(const float4*)(A + (size_t)b * DDIM + col);
        else if (b < NF + NE) v = *(const float4*)(Wr + (size_t)(b - NF) * DDIM + col);
        uint2 p; p.x = f2bf(v.x, v.y); p.y = f2bf(v.z, v.w);
        *(uint2*)(Abt + (size_t)b * DDIM + col) = p;
    } else {
        const int idx = (b - FP) * 1024 + t * 4;      // over [2][1024][64]
        const int g = idx >> 16, o = (idx >> 6) & 1023, er = idx & 63;
        const int e = er >> 3, r0 = er & 7;           // r0 in {0,4}
        float4 v = *(const float4*)(Bw + ((size_t)(e * 2 + g) * ODIM + o) * 8 + r0);
        uint2 p; p.x = f2bf(v.x, v.y); p.y = f2bf(v.z, v.w);
        *(uint2*)(Bbt + idx) = p;
    }
}

// ---------------------------------------------------------------------------
// Fused: per 32-token tile:
//   phase 1: MFMA GEMM1 x*Abt^T -> h[32][144] (tile 8 = logits), with the
//            zero middle-third output stores interleaved into the K-loop
//   phase 2: softmax+route-weight in LDS; GEMM2 vs L2-resident Bbt -> out
__global__ __launch_bounds__(256) void k_fused(const float* __restrict__ x,
                                               const unsigned short* __restrict__ Abt,
                                               const unsigned short* __restrict__ Bbt,
                                               float* __restrict__ out) {
    __shared__ __align__(16) char smem[50688];
    short* xs  = (short*)smem;             // [2][32][72] bf16
    short* as_ = (short*)(smem + 9216);    // [2][144][72] bf16
    float* hsm = (float*)smem;             // [32][148] fp32 (alias, after loop)

    const int t    = threadIdx.x;
    const int tokb = blockIdx.x * TOKB;
    const int lane = t & 63, w = t >> 6;
    const int l15  = lane & 15, lq = lane >> 4;

    // wave -> GEMM1 N-tiles: w0:{0,1,8(logits)}, w1:{2,3}, w2:{4,5}, w3:{6,7}
    const int n0 = (w == 0) ? 0 : 2 * w;
    const int n1 = (w == 0) ? 1 : 2 * w + 1;

    f32x4 a00 = {0,0,0,0}, a01 = {0,0,0,0}, a02 = {0,0,0,0};
    f32x4 a10 = {0,0,0,0}, a11 = {0,0,0,0}, a12 = {0,0,0,0};

    float4 xr[2];
    uint4  ar[5];

    auto LD = [&](int k0) {   // issue global loads into regs
#pragma unroll
        for (int i = 0; i < 2; ++i) {
            int c = t + i * 256, tok = c >> 4, kq = c & 15;
            xr[i] = *(const float4*)(x + (size_t)(tokb + tok) * DDIM + k0 + kq * 4);
        }
#pragma unroll
        for (int i = 0; i < 5; ++i) {
            int c = t + i * 256;
            if (c < 1152) {
                int row = c >> 3, c8 = c & 7;
                ar[i] = *(const uint4*)(Abt + (size_t)row * DDIM + k0 + c8 * 8);
            }
        }
    };
    auto WR = [&](int buf) {  // cvt + LDS writes
        short* xb = xs + buf * (TOKB * 72);
        short* ab = as_ + buf * (144 * 72);
#pragma unroll
        for (int i = 0; i < 2; ++i) {
            int c = t + i * 256, tok = c >> 4, kq = c & 15;
            uint2 p; p.x = f2bf(xr[i].x, xr[i].y); p.y = f2bf(xr[i].z, xr[i].w);
            *(uint2*)(xb + tok * 72 + kq * 4) = p;
        }
#pragma unroll
        for (int i = 0; i < 5; ++i) {
            int c = t + i * 256;
            if (c < 1152) {
                int row = c >> 3, c8 = c & 7;
                *(uint4*)(ab + row * 72 + c8 * 8) = ar[i];
            }
        }
    };

    LD(0);
    WR(0);
    const float4 zf4 = {0.f, 0.f, 0.f, 0.f};
    for (int s = 0; s < 16; ++s) {
        const int cur = s & 1;
        __syncthreads();
        if (s < 15) LD((s + 1) * 64);
        // interleaved zero-fill of disabled middle third (cols 1024..2047):
        // 512 float4 per step x 16 steps = 32x1024 floats
        {
            int zi = s * 512 + t;
            int tok0 = zi >> 8, c40 = zi & 255;
            *(float4*)(out + (size_t)(tokb + tok0) * NOUT + 1024 + c40 * 4) = zf4;
            int zj = zi + 256;
            int tok1 = zj >> 8, c41 = zj & 255;
            *(float4*)(out + (size_t)(tokb + tok1) * NOUT + 1024 + c41 * 4) = zf4;
        }
        const short* xb = xs + cur * (TOKB * 72);
        const short* ab = as_ + cur * (144 * 72);
#pragma unroll
        for (int ks = 0; ks < 2; ++ks) {
            bf16x8 af0 = *(const bf16x8*)(xb + l15 * 72 + ks * 32 + lq * 8);
            bf16x8 af1 = *(const bf16x8*)(xb + (16 + l15) * 72 + ks * 32 + lq * 8);
            bf16x8 b0 = *(const bf16x8*)(ab + (n0 * 16 + l15) * 72 + ks * 32 + lq * 8);
            a00 = __builtin_amdgcn_mfma_f32_16x16x32_bf16(af0, b0, a00, 0, 0, 0);
            a10 = __builtin_amdgcn_mfma_f32_16x16x32_bf16(af1, b0, a10, 0, 0, 0);
            bf16x8 b1 = *(const bf16x8*)(ab + (n1 * 16 + l15) * 72 + ks * 32 + lq * 8);
            a01 = __builtin_amdgcn_mfma_f32_16x16x32_bf16(af0, b1, a01, 0, 0, 0);
            a11 = __builtin_amdgcn_mfma_f32_16x16x32_bf16(af1, b1, a11, 0, 0, 0);
            if (w == 0) {
                bf16x8 b2 = *(const bf16x8*)(ab + (8 * 16 + l15) * 72 + ks * 32 + lq * 8);
                a02 = __builtin_amdgcn_mfma_f32_16x16x32_bf16(af0, b2, a02, 0, 0, 0);
                a12 = __builtin_amdgcn_mfma_f32_16x16x32_bf16(af1, b2, a12, 0, 0, 0);
            }
        }
        if (s < 15) WR(cur ^ 1);
    }
    __syncthreads();

    // acc -> hsm[32][148]  (C/D layout: col=l15, row=lq*4+r per 16-row tile)
#pragma unroll
    for (int r = 0; r < 4; ++r) {
        int row0 = lq * 4 + r, row1 = 16 + lq * 4 + r;
        hsm[row0 * 148 + n0 * 16 + l15] = a00[r];
        hsm[row1 * 148 + n0 * 16 + l15] = a10[r];
        hsm[row0 * 148 + n1 * 16 + l15] = a01[r];
        hsm[row1 * 148 + n1 * 16 + l15] = a11[r];
        if (w == 0) {
            hsm[row0 * 148 + 128 + l15] = a02[r];
            hsm[row1 * 148 + 128 + l15] = a12[r];
        }
    }
    __syncthreads();

    // softmax over experts, fold SCALE
    if (t < TOKB) {
        float m = -1e30f;
#pragma unroll
        for (int e = 0; e < NE; ++e) m = fmaxf(m, hsm[t * 148 + NF + e]);
        float p[NE], sum = 0.f;
#pragma unroll
        for (int e = 0; e < NE; ++e) { p[e] = expf(hsm[t * 148 + NF + e] - m); sum += p[e]; }
        float inv = SCALE / sum;
#pragma unroll
        for (int e = 0; e < NE; ++e) hsm[t * 148 + NF + e] = p[e] * inv;
    }
    __syncthreads();

    // build GEMM2 A-fragments: paf[m][g][ks], route-weighted, cvt to bf16
    bf16x8 paf[2][2][2];
#pragma unroll
    for (int m = 0; m < 2; ++m)
#pragma unroll
        for (int g = 0; g < 2; ++g)
#pragma unroll
            for (int ks = 0; ks < 2; ++ks) {
                int row = m * 16 + l15;
                int e = ks * 4 + lq;
                const float* hp = hsm + row * 148 + e * 16 + g * 8;
                float rt = hsm[row * 148 + NF + e];
                f32x4 v0 = *(const f32x4*)(hp);
                f32x4 v1 = *(const f32x4*)(hp + 4);
                uint4 pk;
                pk.x = f2bf(v0[0] * rt, v0[1] * rt);
                pk.y = f2bf(v0[2] * rt, v0[3] * rt);
                pk.z = f2bf(v1[0] * rt, v1[1] * rt);
                pk.w = f2bf(v1[2] * rt, v1[3] * rt);
                paf[m][g][ks] = *(bf16x8*)&pk;
            }

    // GEMM2: B streamed from L2-resident Bbt; dword stores
#pragma unroll
    for (int g = 0; g < 2; ++g) {
#pragma unroll 4
        for (int nn = 0; nn < 16; ++nn) {
            int n = (w << 4) + nn;
            const unsigned short* bp =
                Bbt + (((size_t)(g << 10) + (n << 4) + l15) << 6) + (lq << 3);
            bf16x8 b0 = *(const bf16x8*)(bp);
            bf16x8 b1 = *(const bf16x8*)(bp + 32);
            f32x4 c0 = {0,0,0,0}, c1 = {0,0,0,0};
            c0 = __builtin_amdgcn_mfma_f32_16x16x32_bf16(paf[0][g][0], b0, c0, 0, 0, 0);
            c0 = __builtin_amdgcn_mfma_f32_16x16x32_bf16(paf[0][g][1], b1, c0, 0, 0, 0);
            c1 = __builtin_amdgcn_mfma_f32_16x16x32_bf16(paf[1][g][0], b0, c1, 0, 0, 0);
            c1 = __builtin_amdgcn_mfma_f32_16x16x32_bf16(paf[1][g][1], b1, c1, 0, 0, 0);
            int col = g * 2048 + (n << 4) + l15;
#pragma unroll
            for (int r = 0; r < 4; ++r) {
                out[(size_t)(tokb + lq * 4 + r) * NOUT + col] = c0[r];
                out[(size_t)(tokb + 16 + lq * 4 + r) * NOUT + col] = c1[r];
            }
        }
    }
}

// ---------------------------------------------------------------------------
extern "C" void kernel_launch(void* const* d_in, const int* in_sizes, int n_in,
                              void* d_out, int out_size, void* d_ws, size_t ws_size,
                              hipStream_t stream) {
    const float* x  = (const float*)d_in[0];
    const float* Wr = (const float*)d_in[1];
    const float* A  = (const float*)d_in[2];
    const float* Bw = (const float*)d_in[3];
    unsigned short* Abt = (unsigned short*)((char*)d_ws + WS_ABT);
    unsigned short* Bbt = (unsigned short*)((char*)d_ws + WS_BBT);
    float* out = (float*)d_out;

    k_prep <<<FP + 128, 256, 0, stream>>>(A, Wr, Bw, Abt, Bbt);
    k_fused<<<NTOK / TOKB, 256, 0, stream>>>(x, Abt, Bbt, out);
}

// Round 4
// 83.710 us; speedup vs baseline: 1.3548x; 1.3548x over previous
//
#include <hip/hip_runtime.h>
#include <math.h>

// MoELoRA dims (fixed by the problem)
#define NTOK   16384      // B*S
#define DDIM   1024
#define NE     8
#define NF     128        // E*G*R down-proj features (f = e*16 + g*8 + r)
#define FP     144        // GEMM1 N: 128 h + 8 logits + 8 zero  (9 MFMA N-tiles)
#define ODIM   1024
#define NOUT   3072
#define SCALE  2.0f
#define TOKB   64         // tokens per block -> 256 blocks (1 per CU)

typedef __attribute__((ext_vector_type(8))) short bf16x8;
typedef __attribute__((ext_vector_type(4))) float f32x4;

// ws layout (bytes)
#define WS_ABT 0                        // bf16 [144][1024]   = 294912 B
#define WS_BBT 294912                   // bf16 [2][1024][64] = 262144 B

// pack two fp32 -> (bf16(a) | bf16(b)<<16), round-to-nearest-even
__device__ inline unsigned f2bf(float a, float b) {
    union { float f; unsigned u; } ua, ub;
    ua.f = a; ub.f = b;
    unsigned x = ua.u + (0x7fffu + ((ua.u >> 16) & 1));
    unsigned y = ub.u + (0x7fffu + ((ub.u >> 16) & 1));
    return (x >> 16) | (y & 0xffff0000u);
}

// ---------------------------------------------------------------------------
// Prep: Abt[f][d] = bf16(concat(A, W_route, 0))   (A is already f-major)
//       Bbt[g][o][er] = bf16(Bw[e][g][o][r]), er = e*8+r
__global__ __launch_bounds__(256) void k_prep(const float* __restrict__ A,
                                              const float* __restrict__ Wr,
                                              const float* __restrict__ Bw,
                                              unsigned short* __restrict__ Abt,
                                              unsigned short* __restrict__ Bbt) {
    const int b = blockIdx.x, t = threadIdx.x;
    if (b < FP) {
        const int col = t * 4;
        float4 v = {0.f, 0.f, 0.f, 0.f};
        if (b < NF)           v = *(const float4*)(A + (size_t)b * DDIM + col);
        else if (b < NF + NE) v = *(const float4*)(Wr + (size_t)(b - NF) * DDIM + col);
        uint2 p; p.x = f2bf(v.x, v.y); p.y = f2bf(v.z, v.w);
        *(uint2*)(Abt + (size_t)b * DDIM + col) = p;
    } else {
        const int idx = (b - FP) * 1024 + t * 4;      // over [2][1024][64]
        const int g = idx >> 16, o = (idx >> 6) & 1023, er = idx & 63;
        const int e = er >> 3, r0 = er & 7;           // r0 in {0,4}
        float4 v = *(const float4*)(Bw + ((size_t)(e * 2 + g) * ODIM + o) * 8 + r0);
        uint2 p; p.x = f2bf(v.x, v.y); p.y = f2bf(v.z, v.w);
        *(uint2*)(Bbt + idx) = p;
    }
}

// ---------------------------------------------------------------------------
// Fused, 64-token tiles, M-split waves (wave w -> tokens w*16..w*16+15):
//  phase 1: K-loop GEMM1 (x * Abt^T -> h[64][144], tile 8 = logits);
//           A-tile via global_load_lds (swizzled), x reg-staged (swizzled);
//           zero-fill of disabled middle third interleaved.
//  phase 2: in-register softmax (shfl butterfly over 8 expert lanes),
//           route-weighted wh -> LDS (wave-private rows), GEMM2 vs L2-hot
//           Bbt, dword stores.
__global__ __launch_bounds__(256) void k_fused(const float* __restrict__ x,
                                               const unsigned short* __restrict__ Abt,
                                               const unsigned short* __restrict__ Bbt,
                                               float* __restrict__ out) {
    __shared__ __align__(16) char smem[53248];
    unsigned short* xs = (unsigned short*)smem;            // [2][64][64] bf16, swizzled
    unsigned short* ab = (unsigned short*)(smem + 16384);  // [2][144][64] bf16, swizzled
    float* whs = (float*)smem;                             // [64][140] fp32 alias (phase 2)

    const int t    = threadIdx.x;
    const int tokb = blockIdx.x * TOKB;
    const int lane = t & 63, w = t >> 6;
    const int l15  = lane & 15, lq = lane >> 4;

    f32x4 acc[9];
#pragma unroll
    for (int n = 0; n < 9; ++n) acc[n] = (f32x4){0.f, 0.f, 0.f, 0.f};

    // x staging: thread covers token t>>2, 16 consecutive floats at (t&3)*16
    const int xtok = t >> 2;
    const int xc   = t & 3;
    float4 xr[4];

    auto LDX = [&](int k0) {
#pragma unroll
        for (int i = 0; i < 4; ++i)
            xr[i] = *(const float4*)(x + (size_t)(tokb + xtok) * DDIM + k0 + xc * 16 + i * 4);
    };
    auto WRX = [&](int buf) {
        unsigned short* xb = xs + buf * (64 * 64);
        uint4 pa, pb;
        pa.x = f2bf(xr[0].x, xr[0].y); pa.y = f2bf(xr[0].z, xr[0].w);
        pa.z = f2bf(xr[1].x, xr[1].y); pa.w = f2bf(xr[1].z, xr[1].w);
        pb.x = f2bf(xr[2].x, xr[2].y); pb.y = f2bf(xr[2].z, xr[2].w);
        pb.z = f2bf(xr[3].x, xr[3].y); pb.w = f2bf(xr[3].z, xr[3].w);
        const int c0 = (xc * 2) ^ (xtok & 7);      // XOR-swizzled 16B chunk
        const int c1 = (xc * 2 + 1) ^ (xtok & 7);
        *(uint4*)(xb + xtok * 64 + c0 * 8) = pa;
        *(uint4*)(xb + xtok * 64 + c1 * 8) = pb;
    };
    // A-tile: 18 KB/step via global_load_lds w16; linear LDS dest, source
    // pre-swizzled so content lands XOR-swizzled (rule #21).
    auto LDA = [&](int buf, int k0) {
        unsigned short* base = ab + buf * (144 * 64);
#pragma unroll
        for (int i = 0; i < 5; ++i) {
            if (i < 4 || t < 128) {            // tail: waves 0,1 only
                const int c   = i * 256 + t;
                const int row = c >> 3;
                const int c8  = (c & 7) ^ (row & 7);
                const unsigned short* gp = Abt + (size_t)row * DDIM + k0 + c8 * 8;
                unsigned short* lp = base + (i * 256 + w * 64) * 8;  // wave-uniform
                __builtin_amdgcn_global_load_lds(
                    (const __attribute__((address_space(1))) unsigned int*)gp,
                    (__attribute__((address_space(3))) unsigned int*)lp, 16, 0, 0);
            }
        }
    };

    LDX(0);
    LDA(0, 0);
    WRX(0);
    const float4 zf4 = {0.f, 0.f, 0.f, 0.f};
    for (int s = 0; s < 16; ++s) {
        const int cur = s & 1;
        __syncthreads();                        // buf[cur] ready (drains vm+lgkm)
        if (s < 15) { LDX((s + 1) * 64); LDA(cur ^ 1, (s + 1) * 64); }
        // zero-fill disabled middle third: 16 KB/step, coalesced
#pragma unroll
        for (int i = 0; i < 4; ++i) {
            int j = s * 1024 + i * 256 + t;
            int tok = j >> 8, c4 = j & 255;
            *(float4*)(out + (size_t)(tokb + tok) * NOUT + 1024 + c4 * 4) = zf4;
        }
        const unsigned short* xb  = xs + cur * (64 * 64);
        const unsigned short* abc = ab + cur * (144 * 64);
#pragma unroll
        for (int ks = 0; ks < 2; ++ks) {
            const int sw = (((ks << 2) | lq) ^ (l15 & 7)) * 8;
            bf16x8 af = *(const bf16x8*)(xb + (w * 16 + l15) * 64 + sw);
#pragma unroll
            for (int n = 0; n < 9; ++n) {
                bf16x8 bf = *(const bf16x8*)(abc + (n * 16 + l15) * 64 + sw);
                acc[n] = __builtin_amdgcn_mfma_f32_16x16x32_bf16(af, bf, acc[n], 0, 0, 0);
            }
        }
        if (s < 15) WRX(cur ^ 1);
    }

    // ---- in-register softmax over experts (logits: acc[8], lanes l15<8) ----
    float mx[4], pv[4], sm[4], rt[4];
#pragma unroll
    for (int r = 0; r < 4; ++r) mx[r] = acc[8][r];
#pragma unroll
    for (int m = 1; m <= 4; m <<= 1)
#pragma unroll
        for (int r = 0; r < 4; ++r) mx[r] = fmaxf(mx[r], __shfl_xor(mx[r], m, 16));
#pragma unroll
    for (int r = 0; r < 4; ++r) { pv[r] = expf(acc[8][r] - mx[r]); sm[r] = pv[r]; }
#pragma unroll
    for (int m = 1; m <= 4; m <<= 1)
#pragma unroll
        for (int r = 0; r < 4; ++r) sm[r] += __shfl_xor(sm[r], m, 16);
#pragma unroll
    for (int r = 0; r < 4; ++r) rt[r] = SCALE * pv[r] / sm[r];

    __syncthreads();   // xs/ab dead; whs alias becomes live

    // route-weighted wh -> LDS (wave-private rows w*16..w*16+15)
#pragma unroll
    for (int e = 0; e < NE; ++e) {
        float rb[4];
#pragma unroll
        for (int r = 0; r < 4; ++r) rb[r] = __shfl(rt[r], e, 16);
#pragma unroll
        for (int r = 0; r < 4; ++r)
            whs[(w * 16 + lq * 4 + r) * 140 + e * 16 + l15] = acc[e][r] * rb[r];
    }

    // GEMM2 A-fragments from own rows (within-wave LDS dep, no barrier)
    bf16x8 paf[2][2];   // [g][ks]
#pragma unroll
    for (int g = 0; g < 2; ++g)
#pragma unroll
        for (int ks = 0; ks < 2; ++ks) {
            const float* hp = whs + (w * 16 + l15) * 140 + ((ks << 2) | lq) * 16 + (g << 3);
            f32x4 v0 = *(const f32x4*)hp;
            f32x4 v1 = *(const f32x4*)(hp + 4);
            uint4 pk;
            pk.x = f2bf(v0[0], v0[1]); pk.y = f2bf(v0[2], v0[3]);
            pk.z = f2bf(v1[0], v1[1]); pk.w = f2bf(v1[2], v1[3]);
            paf[g][ks] = *(bf16x8*)&pk;
        }

    // GEMM2: wave w covers rows w*16..+15 x all 2048 enabled cols
#pragma unroll 1
    for (int g = 0; g < 2; ++g) {
#pragma unroll 4
        for (int n = 0; n < 64; ++n) {
            const unsigned short* bp =
                Bbt + ((size_t)(g << 10) + (n << 4) + l15) * 64 + (lq << 3);
            bf16x8 b0 = *(const bf16x8*)bp;
            bf16x8 b1 = *(const bf16x8*)(bp + 32);
            f32x4 c = {0.f, 0.f, 0.f, 0.f};
            c = __builtin_amdgcn_mfma_f32_16x16x32_bf16(paf[g][0], b0, c, 0, 0, 0);
            c = __builtin_amdgcn_mfma_f32_16x16x32_bf16(paf[g][1], b1, c, 0, 0, 0);
            const int col = (g << 11) + (n << 4) + l15;
            float* op = out + (size_t)(tokb + w * 16 + lq * 4) * NOUT + col;
#pragma unroll
            for (int r = 0; r < 4; ++r) op[(size_t)r * NOUT] = c[r];
        }
    }
}

// ---------------------------------------------------------------------------
extern "C" void kernel_launch(void* const* d_in, const int* in_sizes, int n_in,
                              void* d_out, int out_size, void* d_ws, size_t ws_size,
                              hipStream_t stream) {
    const float* x  = (const float*)d_in[0];
    const float* Wr = (const float*)d_in[1];
    const float* A  = (const float*)d_in[2];
    const float* Bw = (const float*)d_in[3];
    unsigned short* Abt = (unsigned short*)((char*)d_ws + WS_ABT);
    unsigned short* Bbt = (unsigned short*)((char*)d_ws + WS_BBT);
    float* out = (float*)d_out;

    k_prep <<<FP + 128, 256, 0, stream>>>(A, Wr, Bw, Abt, Bbt);
    k_fused<<<NTOK / TOKB, 256, 0, stream>>>(x, Abt, Bbt, out);
}